// Round 16
// baseline (37135.117 us; speedup 1.0000x reference)
//
#include <hip/hip_runtime.h>
#include <stdint.h>

// Problem constants
#define HD       64
#define MM       256
#define BB       1024
#define LL       2048
#define SCALE_   0.125f
#define ETHRESH_VERIFY 2.55f
#define GATE_SUM (2560ull << 20)
#define M30      0x3FFFFFFFull
#define M25      0x1FFFFFFull
#define SPIN_MAND (1 << 17)
#define SPIN_POLL 8192
#define SPIN_LDS (1 << 22)

// ---------------- workspace (d_ws) layout, bytes (unchanged) ----------------
#define WS_RING  0
#define WS_MIRR  16384
#define WS_FLAG  32768
#define WS_WPA   32832       // [32 q][192 row] u32 bf16-pairs of w_ih r-cols
#define WS_WPB   57408       // same for w_hh
#define WS_G     81984       // [64 tok][96] u32 bf16 pairs
#define WS_HWT2  106560      // [32 hp][64 o] float2 f32 head_w pairs
#define WS_W2    122944      // [64][64] f32 wk^T@wq
#define WS_D     139328
#define WS_E     139584
#define WS_F     139840

// ---------------- FAST kernel LDS layout ----------------
#define FK_WHH4  0           // uint4[32][64] (whh r,z,n, pad) = 32768
#define FK_WR4   32768       // uint4[32][64] (wr r,z,n, pad)  = 32768
#define FK_G     65536       // 24576
#define FK_HWF   90112       // float4[16][64] f32 head_w      = 16384
#define FK_DYN   106496      // 4 b * 4096
#define FKD_STRIDE 4096
#define FKD_GI   0           // 192 f32
#define FKD_GH   768         // 192 f32
#define FKD_HA   1536        // 64 f32 (half0's h copy)
#define FKD_HB   1792        // 64 f32 (half1's h copy)
#define FKD_NUM  2048        // 128 f32
#define FKD_WEA  2560        // 128 f32
#define FKD_WEB  3072        // 128 f32
#define FKD_SEH  3584        // 2 f32
#define FK_LDS   122880

// fast phase-0 overlay
#define Q0_W2P   0           // 8192
#define Q0_WVT2  8192        // 8192
#define Q0_D     16384
#define Q0_E     16640
#define Q0_F     16896
#define Q0_MC    17408       // + b_local*16640 : [64][65] f32, shared per b

// ---------------- FALLBACK kernel LDS layout (unchanged, proven) ----------------
#define LD_WPA   0
#define LD_WPB   24576
#define LD_G     49152
#define LD_HWT2  73728
#define LD_DYN   90112
#define DYN_STRIDE 6656
#define DY_GI    0
#define DY_GH    1536
#define DY_H0A   2304
#define DY_H1A   2560
#define DY_H0B   2816
#define DY_H1B   3072
#define DY_NUM   3328
#define DY_WEA   4352
#define DY_WEB   5376
#define DY_SEH   6400
#define LD_MISC  116736
#define P0_W2P   0
#define P0_WVT2  8192
#define P0_D     16384
#define P0_E     16640
#define P0_F     16896
#define P0_MC    17408
#define MC_BYTES 16640
#define LDS_BYTES 150528

__device__ __forceinline__ unsigned bf16r(float x) {
  unsigned u = __float_as_uint(x);
  return (u + 0x7fffu + ((u >> 16) & 1u)) >> 16;
}
__device__ __forceinline__ unsigned pack2(float a, float b) {
  return bf16r(a) | (bf16r(b) << 16);
}
__device__ __forceinline__ float lo16(unsigned u) { return __uint_as_float(u << 16); }
__device__ __forceinline__ float hi16(unsigned u) { return __uint_as_float(u & 0xffff0000u); }

#define WAVE_FENCE() asm volatile("s_waitcnt lgkmcnt(0)" ::: "memory")

// =====================================================================
// P1: one-time weight preprocessing into workspace (unchanged)
// =====================================================================
extern "C" __global__ void reactive_pre(
    const float* __restrict__ embed, const float* __restrict__ w_ih,
    const float* __restrict__ w_hh,  const float* __restrict__ b_ih,
    const float* __restrict__ wq,    const float* __restrict__ bq,
    const float* __restrict__ wk,    const float* __restrict__ bk,
    const float* __restrict__ head_w, unsigned char* __restrict__ ws)
{
  const int tid = threadIdx.x;  // 1024 threads, 1 block

  unsigned* wpa = (unsigned*)(ws + WS_WPA);
  unsigned* wpb = (unsigned*)(ws + WS_WPB);
  for (int i = tid; i < 6144; i += 1024) {
    int q = i / 192, row = i % 192;
    wpa[i] = pack2(w_ih[row * 128 + 64 + 2 * q], w_ih[row * 128 + 64 + 2 * q + 1]);
    wpb[i] = pack2(w_hh[row * 64 + 2 * q],       w_hh[row * 64 + 2 * q + 1]);
  }
  unsigned* gp = (unsigned*)(ws + WS_G);
  for (int i = tid; i < 64 * 96; i += 1024) {
    int v = i / 96, u = i % 96;
    int j0 = 2 * u, j1 = j0 + 1;
    float g0 = b_ih[j0], g1 = b_ih[j1];
    for (int h = 0; h < 64; ++h) {
      float ev = embed[v * 64 + h];
      g0 = fmaf(ev, w_ih[j0 * 128 + h], g0);
      g1 = fmaf(ev, w_ih[j1 * 128 + h], g1);
    }
    gp[i] = pack2(g0, g1);
  }
  float2* hwt2 = (float2*)(ws + WS_HWT2);
  for (int i = tid; i < 2048; i += 1024) {
    int hp = i >> 6, o = i & 63;
    hwt2[i] = make_float2(head_w[o * 64 + 2 * hp], head_w[o * 64 + 2 * hp + 1]);
  }
  float* w2 = (float*)(ws + WS_W2);
  for (int i = tid; i < 4096; i += 1024) {
    int h2 = i >> 6, h = i & 63;
    float a = 0.f;
    for (int o = 0; o < 64; ++o) a = fmaf(wk[o * 64 + h2], wq[o * 64 + h], a);
    w2[i] = a;
  }
  if (tid < 64) {
    float a = 0.f, b2 = 0.f;
    for (int o = 0; o < 64; ++o) a  = fmaf(bk[o], wq[o * 64 + tid], a);
    for (int o = 0; o < 64; ++o) b2 = fmaf(bq[o], wk[o * 64 + tid], b2);
    ((float*)(ws + WS_D))[tid] = a;
    ((float*)(ws + WS_E))[tid] = b2;
  }
  if (tid == 0) {
    float a = 0.f;
    for (int o = 0; o < 64; ++o) a = fmaf(bq[o], bk[o], a);
    *(float*)(ws + WS_F) = a;
  }
}

// Phase-0 chunk TT (global m rows TT*64..TT*64+63). Both waves of b load
// 32 rows each into the shared mc; the owner half computes K'+V into its
// compile-time-selected register arrays.
template<int TT>
__device__ __forceinline__ void p0_chunk(
    bool own, int lane, int r0, float* mc, const float* memb,
    const float* pD, const float* pE, const unsigned* w2p, const unsigned* wvt2,
    float bvl, float fscal, unsigned (&kpg)[32], float& cmg, unsigned (&vtg)[32])
{
  __syncthreads();
#pragma unroll 4
  for (int r = 0; r < 32; ++r)
    mc[(r0 + r) * 65 + lane] = memb[(size_t)(TT * 64 + r0 + r) * 64 + lane];
  __syncthreads();

  if (own) {
    float acc[64];
#pragma unroll
    for (int h = 0; h < 64; ++h) acc[h] = pD[h];
    float cacc = fscal;
    for (int h2 = 0; h2 < 64; ++h2) {
      float mv = mc[lane * 65 + h2];
      cacc = fmaf(mv, pE[h2], cacc);
      const unsigned* wrow = w2p + h2 * 32;
#pragma unroll
      for (int hp = 0; hp < 32; ++hp) {
        unsigned u = wrow[hp];
        acc[2 * hp]     = fmaf(mv, lo16(u), acc[2 * hp]);
        acc[2 * hp + 1] = fmaf(mv, hi16(u), acc[2 * hp + 1]);
      }
    }
    cmg = cacc;
#pragma unroll
    for (int u = 0; u < 32; ++u) kpg[u] = pack2(acc[2 * u], acc[2 * u + 1]);

#pragma unroll
    for (int rp = 0; rp < 32; ++rp) {
      float a0 = bvl, a1 = bvl;
#pragma unroll
      for (int hq = 0; hq < 32; ++hq) {
        unsigned w = wvt2[hq * 64 + lane];
        float wl = lo16(w), wh = hi16(w);
        const float2 m0 = *(const float2*)&mc[(2 * rp) * 65 + 2 * hq];
        const float2 m1 = *(const float2*)&mc[(2 * rp + 1) * 65 + 2 * hq];
        a0 = fmaf(m0.x, wl, a0); a0 = fmaf(m0.y, wh, a0);
        a1 = fmaf(m1.x, wl, a1); a1 = fmaf(m1.y, wh, a1);
      }
      vtg[rp] = pack2(a0, a1);
    }
  }
}

// =====================================================================
// FAST kernel v4: R13's SYMMETRIC structure (all 8 waves busy each phase)
// with packed memory access: b128 weight reads, float4 h/head_w reads.
// 256 blocks x 512 threads; wave = (half, b_local); per wave: K' (kp0,kp1)
// + V (vt0,vt1) for m in [half*128, half*128+128) resident in registers.
// Speculates cond=TRUE (f32 verify, min-entropy > 2.55); fallback on fail.
// =====================================================================
extern "C" __global__ void __launch_bounds__(512, 1)
reactive_fast(const int* __restrict__ seq, const float* __restrict__ memory,
              const float* __restrict__ wvp, const float* __restrict__ bvp,
              const float* __restrict__ b_hh, const float* __restrict__ head_w,
              const float* __restrict__ head_b, unsigned char* __restrict__ ws,
              float* __restrict__ out)
{
  extern __shared__ __align__(16) unsigned char lds[];
  const int tid     = threadIdx.x;
  const int wv      = tid >> 6;
  const int lane    = tid & 63;
  const int half    = wv >> 2;       // 0 = A (gi+verify), 1 = B (gh)
  const int b_local = wv & 3;
  const int b       = (int)blockIdx.x * 4 + b_local;
  const bool isA    = (half == 0);

  unsigned kp0[32], kp1[32], vt0[32], vt1[32];
  float cm0 = 0.f, cm1 = 0.f;

  // ---------------- phase 0: K'/V for own half into registers ----------------
  {
    unsigned* w2p  = (unsigned*)(lds + Q0_W2P);
    unsigned* wvt2 = (unsigned*)(lds + Q0_WVT2);
    float* pD = (float*)(lds + Q0_D);
    float* pE = (float*)(lds + Q0_E);
    float* pF = (float*)(lds + Q0_F);
    const float* wsW2 = (const float*)(ws + WS_W2);
    for (int i = tid; i < 2048; i += 512) {
      int h2 = i >> 5, hp = i & 31;
      w2p[i] = pack2(wsW2[h2 * 64 + 2 * hp], wsW2[h2 * 64 + 2 * hp + 1]);
    }
    for (int i = tid; i < 2048; i += 512) {
      int h2p = i >> 6, l = i & 63;
      wvt2[i] = pack2(wvp[l * 64 + 2 * h2p], wvp[l * 64 + 2 * h2p + 1]);
    }
    if (tid < 64) { pD[tid] = ((const float*)(ws + WS_D))[tid];
                    pE[tid] = ((const float*)(ws + WS_E))[tid]; }
    if (tid == 0) pF[0] = *(const float*)(ws + WS_F);
    __syncthreads();

    float* mc = (float*)(lds + Q0_MC + b_local * 16640);   // [64][65], shared per b
    const float bvl   = bvp[lane];
    const float fscal = pF[0];
    const float* memb = memory + (size_t)b * (MM * HD);
    const int r0 = isA ? 0 : 32;
    const bool own0 = (half == 0);   // chunks 0,1
    const bool own1 = (half == 1);   // chunks 2,3

    p0_chunk<0>(own0, lane, r0, mc, memb, pD, pE, w2p, wvt2, bvl, fscal, kp0, cm0, vt0);
    p0_chunk<1>(own0, lane, r0, mc, memb, pD, pE, w2p, wvt2, bvl, fscal, kp1, cm1, vt1);
    p0_chunk<2>(own1, lane, r0, mc, memb, pD, pE, w2p, wvt2, bvl, fscal, kp0, cm0, vt0);
    p0_chunk<3>(own1, lane, r0, mc, memb, pD, pE, w2p, wvt2, bvl, fscal, kp1, cm1, vt1);
    __syncthreads();
  }

  // ---------------- stage packed weight tables; init dynamic region ----------------
  {
    const unsigned* wpaW = (const unsigned*)(ws + WS_WPA);
    const unsigned* wpbW = (const unsigned*)(ws + WS_WPB);
    unsigned* sWHH = (unsigned*)(lds + FK_WHH4);
    unsigned* sWRR = (unsigned*)(lds + FK_WR4);
    for (int i = tid; i < 8192; i += 512) {
      int q = i >> 8, rem = i & 255, l = rem >> 2, c = rem & 3;
      sWHH[i] = (c < 3) ? wpbW[q * 192 + c * 64 + l] : 0u;
      sWRR[i] = (c < 3) ? wpaW[q * 192 + c * 64 + l] : 0u;
    }
    const float4* s3 = (const float4*)(ws + WS_G);
    float4* d3 = (float4*)(lds + FK_G);
    for (int i = tid; i < 1536; i += 512) d3[i] = s3[i];
    const float2* hwt2w = (const float2*)(ws + WS_HWT2);
    float4* sHWF = (float4*)(lds + FK_HWF);
    for (int i = tid; i < 1024; i += 512) {
      int j = i >> 6, o = i & 63;
      float2 p0 = hwt2w[(2 * j) * 64 + o];
      float2 p1 = hwt2w[(2 * j + 1) * 64 + o];
      sHWF[i] = make_float4(p0.x, p0.y, p1.x, p1.y);
    }
    float* dz = (float*)(lds + FK_DYN);
    for (int i = tid; i < 4 * FKD_STRIDE / 4; i += 512) dz[i] = 0.f;
    __syncthreads();
    if (tid < 4) {
      float* se = (float*)(lds + FK_DYN + tid * FKD_STRIDE + FKD_SEH);
      se[0] = 1.f; se[1] = 1.f;
    }
    __syncthreads();
  }

  const uint4*  sWHH4 = (const uint4*)(lds + FK_WHH4);
  const uint4*  sWR4  = (const uint4*)(lds + FK_WR4);
  const unsigned* sG  = (const unsigned*)(lds + FK_G);
  const float4* sHWF4 = (const float4*)(lds + FK_HWF);
  unsigned char* dynp = lds + FK_DYN + b_local * FKD_STRIDE;
  float* sGI  = (float*)(dynp + FKD_GI);
  float* sGH  = (float*)(dynp + FKD_GH);
  float* sHme = (float*)(dynp + (isA ? FKD_HA : FKD_HB));
  float* sNUM = (float*)(dynp + FKD_NUM);
  float* sWE  = (float*)(dynp + (isA ? FKD_WEA : FKD_WEB));
  float* sSEH = (float*)(dynp + FKD_SEH);
  unsigned* flag = (unsigned*)(ws + WS_FLAG);
  const int* seqb = seq + (size_t)b * LL;

  float h_reg = 0.f;
  float bh_r = 0.f, bh_z = 0.f, bh_n = 0.f;
  if (!isA) { bh_r = b_hh[lane]; bh_z = b_hh[64 + lane]; bh_n = b_hh[128 + lane]; }
  const float hb_l = head_b[lane];
  float own_r = 0.f, own_z = 0.f, own_n = 0.f;
  bool specOK = true;

  for (int t = 0; t < LL; ++t) {
    // ---- P1: A computes gi = G[token] + (num@Wr)/Se (b128 weights);
    //          B computes gh = h@Whh^T + b_hh (b128 weights) ----
    if (isA) {
      float Se = sSEH[0] + sSEH[1];
      float rcp = 1.0f / Se;
      int token = seqb[t];
      float sr = 0.f, sz = 0.f, sn = 0.f;
      const float2* nm2 = (const float2*)sNUM;
#pragma unroll
      for (int q = 0; q < 32; ++q) {
        float2 n0 = nm2[q];
        float2 n1 = nm2[32 + q];
        float a0 = n0.x + n1.x, a1 = n0.y + n1.y;
        uint4 w = sWR4[q * 64 + lane];
        sr = fmaf(a0, lo16(w.x), sr); sr = fmaf(a1, hi16(w.x), sr);
        sz = fmaf(a0, lo16(w.y), sz); sz = fmaf(a1, hi16(w.y), sz);
        sn = fmaf(a0, lo16(w.z), sn); sn = fmaf(a1, hi16(w.z), sn);
      }
      unsigned gp0 = sG[token * 96 +      (lane >> 1)];
      unsigned gp1 = sG[token * 96 + 32 + (lane >> 1)];
      unsigned gp2 = sG[token * 96 + 64 + (lane >> 1)];
      bool oddl = (lane & 1);
      float g_r = oddl ? hi16(gp0) : lo16(gp0);
      float g_z = oddl ? hi16(gp1) : lo16(gp1);
      float g_n = oddl ? hi16(gp2) : lo16(gp2);
      own_r = fmaf(rcp, sr, g_r);
      own_z = fmaf(rcp, sz, g_z);
      own_n = fmaf(rcp, sn, g_n);
      sGI[lane] = own_r; sGI[64 + lane] = own_z; sGI[128 + lane] = own_n;
    } else {
      float hr = bh_r, hz = bh_z, hn = bh_n;
      const float2* h2p = (const float2*)sHme;   // own copy of h(t-1)
#pragma unroll
      for (int q = 0; q < 32; ++q) {
        float2 h01 = h2p[q];
        uint4 w = sWHH4[q * 64 + lane];
        hr = fmaf(h01.x, lo16(w.x), hr); hr = fmaf(h01.y, hi16(w.x), hr);
        hz = fmaf(h01.x, lo16(w.y), hz); hz = fmaf(h01.y, hi16(w.y), hz);
        hn = fmaf(h01.x, lo16(w.z), hn); hn = fmaf(h01.y, hi16(w.z), hn);
      }
      own_r = hr; own_z = hz; own_n = hn;
      sGH[lane] = hr; sGH[64 + lane] = hz; sGH[128 + lane] = hn;
    }
    __syncthreads();   // X

    // ---- P2: gates (redundant & bit-identical on A and B) ----
    float o1, o2, o3;
    if (isA) { o1 = sGH[lane]; o2 = sGH[64 + lane]; o3 = sGH[128 + lane]; }
    else     { o1 = sGI[lane]; o2 = sGI[64 + lane]; o3 = sGI[128 + lane]; }
    float xr = own_r + o1;
    float xz = own_z + o2;
    float gin_v = isA ? own_n : o3;
    float ghn_v = isA ? o3 : own_n;
    float rg = 1.f / (1.f + __expf(-xr));
    float zg = 1.f / (1.f + __expf(-xz));
    float narg = fmaf(rg, ghn_v, gin_v);
    float eee = __expf(-2.f * narg);
    float ng = (1.f - eee) / (1.f + eee);
    float h_new = (1.f - zg) * ng + zg * h_reg;
    sHme[lane] = h_new;
    WAVE_FENCE();

    // ---- P3 (A only): f32 entropy VERIFY (float4 reads) ----
    if (isA) {
      float lo = hb_l;
      const float4* hme4 = (const float4*)sHme;
#pragma unroll
      for (int j = 0; j < 16; ++j) {
        float4 hv = hme4[j];
        float4 w  = sHWF4[j * 64 + lane];
        lo = fmaf(hv.x, w.x, lo); lo = fmaf(hv.y, w.y, lo);
        lo = fmaf(hv.z, w.z, lo); lo = fmaf(hv.w, w.w, lo);
      }
      float pu = __expf(lo);
      float Ss = pu;
#pragma unroll
      for (int off = 32; off; off >>= 1) Ss += __shfl_xor(Ss, off, 64);
      float pr = pu / Ss;
      float ent = pr * __logf(pr + 1e-8f);
#pragma unroll
      for (int off = 32; off; off >>= 1) ent += __shfl_xor(ent, off, 64);
      if (!(-ent > ETHRESH_VERIFY)) specOK = false;
    }

    // ---- P5: attention on own half (K' in regs, h via float4 reads) ----
    {
      float s0 = cm0, s1 = cm1;
      const float4* hme4 = (const float4*)sHme;
#pragma unroll
      for (int j = 0; j < 16; ++j) {
        float4 hv = hme4[j];
        unsigned u00 = kp0[2 * j], u01 = kp0[2 * j + 1];
        unsigned u10 = kp1[2 * j], u11 = kp1[2 * j + 1];
        s0 = fmaf(hv.x, lo16(u00), s0); s0 = fmaf(hv.y, hi16(u00), s0);
        s0 = fmaf(hv.z, lo16(u01), s0); s0 = fmaf(hv.w, hi16(u01), s0);
        s1 = fmaf(hv.x, lo16(u10), s1); s1 = fmaf(hv.y, hi16(u10), s1);
        s1 = fmaf(hv.z, lo16(u11), s1); s1 = fmaf(hv.w, hi16(u11), s1);
      }
      float e0 = __expf(s0 * SCALE_), e1 = __expf(s1 * SCALE_);
      float seh = e0 + e1;
#pragma unroll
      for (int off = 32; off; off >>= 1) seh += __shfl_xor(seh, off, 64);
      sWE[lane] = e0; sWE[64 + lane] = e1;
      if (lane == 0) sSEH[half] = seh;
      WAVE_FENCE();

      // PV over own half's 128 m (V in regs, exp weights float4)
      float al = 0.f;
      const float4* w4 = (const float4*)sWE;
#pragma unroll
      for (int j = 0; j < 16; ++j) {
        float4 w = w4[j];
        unsigned u0 = vt0[2 * j], u1 = vt0[2 * j + 1];
        al = fmaf(w.x, lo16(u0), al); al = fmaf(w.y, hi16(u0), al);
        al = fmaf(w.z, lo16(u1), al); al = fmaf(w.w, hi16(u1), al);
      }
#pragma unroll
      for (int j = 0; j < 16; ++j) {
        float4 w = w4[16 + j];
        unsigned u0 = vt1[2 * j], u1 = vt1[2 * j + 1];
        al = fmaf(w.x, lo16(u0), al); al = fmaf(w.y, hi16(u0), al);
        al = fmaf(w.z, lo16(u1), al); al = fmaf(w.w, hi16(u1), al);
      }
      sNUM[half * 64 + lane] = al;
    }
    h_reg = h_new;
    __syncthreads();   // W
  }

  // ---- speculation failure -> flag (fallback kernel takes over) ----
  if (isA && !specOK && lane == 0)
    __hip_atomic_store(flag, 1u, __ATOMIC_RELAXED, __HIP_MEMORY_SCOPE_AGENT);

  // ---- final logits with f32 head weights ----
  if (isA) {
    float lof = hb_l;
#pragma unroll 8
    for (int h = 0; h < 64; ++h) lof = fmaf(sHme[h], head_w[lane * 64 + h], lof);
    out[(size_t)b * 64 + lane] = lof;
  }
  if (blockIdx.x == 0 && tid == 0) out[BB * 64] = 1.0f;
}

// =====================================================================
// FALLBACK: full grid-consensus kernel (proven). Runs only if the
// speculation flag is set; otherwise exits immediately.
// =====================================================================
__device__ __forceinline__ int sweep_try(const unsigned long long* ring, int s, int lane,
                                         bool cprev, unsigned long long& dsum, int rounds) {
  const unsigned long long* rb = ring + (((size_t)(s & 7)) << 8) + 4 * lane;
  const unsigned long long want = (unsigned long long)(s + 1);
  unsigned long long v0, v1, v2, v3;
  int r = 0;
  for (;;) {
    v0 = __hip_atomic_load(rb + 0, __ATOMIC_RELAXED, __HIP_MEMORY_SCOPE_AGENT);
    v1 = __hip_atomic_load(rb + 1, __ATOMIC_RELAXED, __HIP_MEMORY_SCOPE_AGENT);
    v2 = __hip_atomic_load(rb + 2, __ATOMIC_RELAXED, __HIP_MEMORY_SCOPE_AGENT);
    v3 = __hip_atomic_load(rb + 3, __ATOMIC_RELAXED, __HIP_MEMORY_SCOPE_AGENT);
    bool ok = ((v0 >> 50) == want) && ((v1 >> 50) == want) &&
              ((v2 >> 50) == want) && ((v3 >> 50) == want);
    if (__all(ok)) break;
    if (++r >= rounds) return 0;
    __builtin_amdgcn_s_sleep(1);
  }
  unsigned long long d;
  if (cprev) d = ((v0 >> 25) & M25) + ((v1 >> 25) & M25) +
                 ((v2 >> 25) & M25) + ((v3 >> 25) & M25);
  else       d = (v0 & M25) + (v1 & M25) + (v2 & M25) + (v3 & M25);
#pragma unroll
  for (int off = 32; off; off >>= 1) d += __shfl_xor(d, off, 64);
  dsum = d;
  return 1;
}

__device__ __forceinline__ void root_adv(unsigned long long* ring, unsigned long long* mirr,
                                         volatile unsigned* sCONDW, int lane, int target,
                                         int rounds, int& cnt, unsigned& bits,
                                         bool& cprev, int& rc) {
  while (cnt < target) {
    unsigned long long ds;
    if (!sweep_try(ring, cnt, lane, cprev, ds, rounds)) break;
    cprev = ds > GATE_SUM; rc += cprev ? 1 : 0;
    bits = (bits << 1) | (cprev ? 1u : 0u); ++cnt;
    unsigned long long mv = ((unsigned long long)cnt << 32) | bits;
    for (int i = lane; i < 256; i += 64)
      __hip_atomic_store(mirr + (size_t)i * 8, mv,
                         __ATOMIC_RELAXED, __HIP_MEMORY_SCOPE_AGENT);
    if (lane == 0) *sCONDW = ((unsigned)cnt << 8) | (bits & 0xFFu);
  }
}

__device__ __forceinline__ void mirr_refresh(const unsigned long long* myMirr,
                                             volatile unsigned* sCONDW, int lane,
                                             int& cnt, unsigned& bits) {
  unsigned hi = 0, lo = 0;
  if (lane == 0) {
    unsigned long long v = __hip_atomic_load(myMirr, __ATOMIC_RELAXED,
                                             __HIP_MEMORY_SCOPE_AGENT);
    hi = (unsigned)(v >> 32); lo = (unsigned)v;
  }
  hi = (unsigned)__shfl((int)hi, 0, 64);
  lo = (unsigned)__shfl((int)lo, 0, 64);
  if ((int)hi > cnt) {
    cnt = (int)hi; bits = lo;
    if (lane == 0) *sCONDW = ((unsigned)cnt << 8) | (bits & 0xFFu);
  }
}

extern "C" __global__ void __launch_bounds__(512, 2)
reactive_full(const int* __restrict__ seq, const float* __restrict__ memory,
              const float* __restrict__ wvp, const float* __restrict__ bvp,
              const float* __restrict__ b_hh, const float* __restrict__ head_w,
              const float* __restrict__ head_b, unsigned char* __restrict__ ws,
              float* __restrict__ out)
{
  if (__hip_atomic_load((unsigned*)(ws + WS_FLAG), __ATOMIC_RELAXED,
                        __HIP_MEMORY_SCOPE_AGENT) == 0u)
    return;   // speculation held; fast kernel's output stands

  extern __shared__ __align__(16) unsigned char lds[];
  const int tid     = threadIdx.x;
  const int wv      = tid >> 6;
  const int lane    = tid & 63;
  const int half    = wv >> 2;
  const int b_local = wv & 3;
  const int b       = (int)blockIdx.x * 4 + b_local;
  const bool isA    = (half == 0);
  const bool isRoot = (blockIdx.x == 0);

  unsigned kp[2][32];
  unsigned vt[64];
  float    cm[2];

  {
    unsigned* w2p  = (unsigned*)(lds + P0_W2P);
    unsigned* wvt2 = (unsigned*)(lds + P0_WVT2);
    float* pD = (float*)(lds + P0_D);
    float* pE = (float*)(lds + P0_E);
    float* pF = (float*)(lds + P0_F);
    const float* wsW2 = (const float*)(ws + WS_W2);
    for (int i = tid; i < 2048; i += 512) {
      int h2 = i >> 5, hp = i & 31;
      w2p[i] = pack2(wsW2[h2 * 64 + 2 * hp], wsW2[h2 * 64 + 2 * hp + 1]);
    }
    for (int i = tid; i < 2048; i += 512) {
      int h2p = i >> 6, l = i & 63;
      wvt2[i] = pack2(wvp[l * 64 + 2 * h2p], wvp[l * 64 + 2 * h2p + 1]);
    }
    if (tid < 64) { pD[tid] = ((const float*)(ws + WS_D))[tid];
                    pE[tid] = ((const float*)(ws + WS_E))[tid]; }
    if (tid == 0) pF[0] = *(const float*)(ws + WS_F);
    __syncthreads();

    float* mc = (float*)(lds + P0_MC + wv * MC_BYTES);
    const float bvl   = bvp[lane];
    const float fscal = pF[0];
    const float* memb = memory + ((size_t)b * MM + (size_t)half * 128) * HD;

    for (int g = 0; g < 2; ++g) {
      WAVE_FENCE();
#pragma unroll 4
      for (int r = 0; r < 64; ++r)
        mc[r * 65 + lane] = memb[(size_t)(g * 64 + r) * HD + lane];
      WAVE_FENCE();

      float acc[64];
#pragma unroll
      for (int h = 0; h < 64; ++h) acc[h] = pD[h];
      float cacc = fscal;
      for (int h2 = 0; h2 < 64; ++h2) {
        float mv = mc[lane * 65 + h2];
        cacc = fmaf(mv, pE[h2], cacc);
        const unsigned* wrow = w2p + h2 * 32;
#pragma unroll
        for (int hp = 0; hp < 32; ++hp) {
          unsigned u = wrow[hp];
          acc[2 * hp]     = fmaf(mv, lo16(u), acc[2 * hp]);
          acc[2 * hp + 1] = fmaf(mv, hi16(u), acc[2 * hp + 1]);
        }
      }
      cm[g] = cacc;
#pragma unroll
      for (int u = 0; u < 32; ++u) kp[g][u] = pack2(acc[2 * u], acc[2 * u + 1]);

      for (int rp = 0; rp < 32; ++rp) {
        float a0 = bvl, a1 = bvl;
#pragma unroll
        for (int hq = 0; hq < 32; ++hq) {
          unsigned w = wvt2[hq * 64 + lane];
          float wl = lo16(w), wh = hi16(w);
          const float2 m0 = *(const float2*)&mc[(2 * rp) * 65 + 2 * hq];
          const float2 m1 = *(const float2*)&mc[(2 * rp + 1) * 65 + 2 * hq];
          a0 = fmaf(m0.x, wl, a0); a0 = fmaf(m0.y, wh, a0);
          a1 = fmaf(m1.x, wl, a1); a1 = fmaf(m1.y, wh, a1);
        }
        vt[32 * g + rp] = pack2(a0, a1);
      }
    }
    __syncthreads();
  }

  {
    const float4* s1 = (const float4*)(ws + WS_WPA);   float4* d1 = (float4*)(lds + LD_WPA);
    for (int i = tid; i < 1536; i += 512) d1[i] = s1[i];
    const float4* s2 = (const float4*)(ws + WS_WPB);   float4* d2 = (float4*)(lds + LD_WPB);
    for (int i = tid; i < 1536; i += 512) d2[i] = s2[i];
    const float4* s3 = (const float4*)(ws + WS_G);     float4* d3 = (float4*)(lds + LD_G);
    for (int i = tid; i < 1536; i += 512) d3[i] = s3[i];
    const float4* s4 = (const float4*)(ws + WS_HWT2);  float4* d4 = (float4*)(lds + LD_HWT2);
    for (int i = tid; i < 1024; i += 512) d4[i] = s4[i];
    float* dz = (float*)(lds + LD_DYN);
    for (int i = tid; i < 4 * DYN_STRIDE / 4; i += 512) dz[i] = 0.f;
    if (tid < 5) ((unsigned*)(lds + LD_MISC))[tid] = 0u;
    __syncthreads();
    if (tid < 4) {
      float* se = (float*)(lds + LD_DYN + tid * DYN_STRIDE + DY_SEH);
      se[0] = 1.f; se[1] = 1.f; se[2] = 1.f; se[3] = 1.f;
    }
    __syncthreads();
  }

  const unsigned* sWPA = (const unsigned*)(lds + LD_WPA);
  const unsigned* sWPB = (const unsigned*)(lds + LD_WPB);
  const unsigned* sG   = (const unsigned*)(lds + LD_G);
  const float2*   sHW2 = (const float2*)(lds + LD_HWT2);
  unsigned char* dynp = lds + LD_DYN + b_local * DYN_STRIDE;
  float* sGI   = (float*)(dynp + DY_GI);
  float* sGH   = (float*)(dynp + DY_GH);
  float* sH0me = (float*)(dynp + (isA ? DY_H0A : DY_H0B));
  float* sH1me = (float*)(dynp + (isA ? DY_H1A : DY_H1B));
  float* sNUM  = (float*)(dynp + DY_NUM);
  float* sWE   = (float*)(dynp + (isA ? DY_WEA : DY_WEB));
  float* sSEH  = (float*)(dynp + DY_SEH);
  unsigned long long* sBEC = (unsigned long long*)(lds + LD_MISC);
  volatile unsigned* sCONDW = (volatile unsigned*)(lds + LD_MISC + 16);
  unsigned long long* ring = (unsigned long long*)(ws + WS_RING);
  unsigned long long* mirr = (unsigned long long*)(ws + WS_MIRR);
  unsigned long long* myMirr = mirr + (size_t)blockIdx.x * 8;
  const int* seqb = seq + (size_t)b * LL;

  float h0_reg = 0.f, h1_reg = 0.f, h_reg = 0.f;
  int cnt = 0, rc = 0;
  unsigned bits = 0;
  bool cprev = false;

  float bh_r = 0.f, bh_z = 0.f, bh_n = 0.f;
  if (!isA) { bh_r = b_hh[lane]; bh_z = b_hh[64 + lane]; bh_n = b_hh[128 + lane]; }
  const float hb_l = head_b[lane];

  float a_gr = 0.f, a_gz = 0.f, a_gn = 0.f, a_dr = 0.f, a_dz = 0.f, a_dn = 0.f;
  float b_hr = 0.f, b_hz = 0.f, b_hn = 0.f;

  for (int t = 0; t < LL; ++t) {
    bool c2 = false;
    if (wv == 0) {
      if (isRoot) {
        while (cnt < t - 1) {
          unsigned long long ds;
          if (!sweep_try(ring, cnt, lane, cprev, ds, SPIN_MAND)) ds = 0;
          cprev = ds > GATE_SUM; rc += cprev ? 1 : 0;
          bits = (bits << 1) | (cprev ? 1u : 0u); ++cnt;
          unsigned long long mv = ((unsigned long long)cnt << 32) | bits;
          for (int i = lane; i < 256; i += 64)
            __hip_atomic_store(mirr + (size_t)i * 8, mv,
                               __ATOMIC_RELAXED, __HIP_MEMORY_SCOPE_AGENT);
          if (lane == 0) *sCONDW = ((unsigned)cnt << 8) | (bits & 0xFFu);
        }
        root_adv(ring, mirr, sCONDW, lane, t, 2, cnt, bits, cprev, rc);
        if (t >= 2) {
          int off = cnt - (t - 1);
          c2 = ((bits >> off) & 1u) != 0u;
        }
      } else if (t >= 2) {
        int guard = SPIN_POLL;
        for (;;) {
          mirr_refresh(myMirr, sCONDW, lane, cnt, bits);
          if (cnt >= t - 1) break;
          if (--guard <= 0) break;
          __builtin_amdgcn_s_sleep(8);
        }
        int off = cnt - (t - 1);
        c2 = (off >= 0 && off < 8) ? (((bits >> off) & 1u) != 0u) : false;
      }
    } else if (t >= 2) {
      unsigned cv; int guard = SPIN_LDS;
      for (;;) {
        cv = *sCONDW;
        if ((int)(cv >> 8) >= t - 1) break;
        if (--guard <= 0) break;
        __builtin_amdgcn_s_sleep(0);
      }
      int off = (int)(cv >> 8) - (t - 1);
      c2 = (off >= 0 && off < 8) ? (((cv >> off) & 1u) != 0u) : false;
    }
    h_reg = c2 ? h1_reg : h0_reg;

    if (isA) {
      float Se = sSEH[c2 ? 2 : 0] + sSEH[c2 ? 3 : 1];
      float rcpSe = 1.0f / Se;
      const float* nm = sNUM + (c2 ? 128 : 0);
      int token = seqb[t];
      float sr = 0.f, sz = 0.f, sn = 0.f;
#pragma unroll
      for (int q = 0; q < 32; ++q) {
        float2 n0 = *(const float2*)&nm[2 * q];
        float2 n1 = *(const float2*)&nm[64 + 2 * q];
        float a0 = n0.x + n1.x, a1 = n0.y + n1.y;
        unsigned ur = sWPA[q * 192 + lane];
        unsigned uz = sWPA[q * 192 + 64 + lane];
        unsigned un = sWPA[q * 192 + 128 + lane];
        sr = fmaf(a0, lo16(ur), sr); sr = fmaf(a1, hi16(ur), sr);
        sz = fmaf(a0, lo16(uz), sz); sz = fmaf(a1, hi16(uz), sz);
        sn = fmaf(a0, lo16(un), sn); sn = fmaf(a1, hi16(un), sn);
      }
      unsigned gp0 = sG[token * 96 +      (lane >> 1)];
      unsigned gp1 = sG[token * 96 + 32 + (lane >> 1)];
      unsigned gp2 = sG[token * 96 + 64 + (lane >> 1)];
      bool oddl = (lane & 1);
      a_gr = oddl ? hi16(gp0) : lo16(gp0);
      a_gz = oddl ? hi16(gp1) : lo16(gp1);
      a_gn = oddl ? hi16(gp2) : lo16(gp2);
      a_dr = rcpSe * sr; a_dz = rcpSe * sz; a_dn = rcpSe * sn;
      sGI[lane] = a_gr;        sGI[64 + lane] = a_gz;  sGI[128 + lane] = a_gn;
      sGI[192 + lane] = a_dr;  sGI[256 + lane] = a_dz; sGI[320 + lane] = a_dn;
    } else {
      const float* hprev = c2 ? sH1me : sH0me;
      float hr = bh_r, hz = bh_z, hn = bh_n;
#pragma unroll
      for (int q = 0; q < 32; ++q) {
        float2 h01 = *(const float2*)&hprev[2 * q];
        unsigned ur = sWPB[q * 192 + lane];
        unsigned uz = sWPB[q * 192 + 64 + lane];
        unsigned un = sWPB[q * 192 + 128 + lane];
        hr = fmaf(h01.x, lo16(ur), hr); hr = fmaf(h01.y, hi16(ur), hr);
        hz = fmaf(h01.x, lo16(uz), hz); hz = fmaf(h01.y, hi16(uz), hz);
        hn = fmaf(h01.x, lo16(un), hn); hn = fmaf(h01.y, hi16(un), hn);
      }
      b_hr = hr; b_hz = hz; b_hn = hn;
      sGH[lane] = hr; sGH[64 + lane] = hz; sGH[128 + lane] = hn;
    }
    __syncthreads();

    float gi_r, gi_z, gi_n, da_r, da_z, da_n, gh_r, gh_z, gh_n;
    if (isA) {
      gh_r = sGH[lane]; gh_z = sGH[64 + lane]; gh_n = sGH[128 + lane];
      gi_r = a_gr; gi_z = a_gz; gi_n = a_gn; da_r = a_dr; da_z = a_dz; da_n = a_dn;
    } else {
      gi_r = sGI[lane];       gi_z = sGI[64 + lane];  gi_n = sGI[128 + lane];
      da_r = sGI[192 + lane]; da_z = sGI[256 + lane]; da_n = sGI[320 + lane];
      gh_r = b_hr; gh_z = b_hz; gh_n = b_hn;
    }
    float xr0 = gi_r + gh_r, xz0 = gi_z + gh_z;
    float rg0 = 1.f / (1.f + __expf(-xr0));
    float rg1 = 1.f / (1.f + __expf(-(xr0 + da_r)));
    float zg0 = 1.f / (1.f + __expf(-xz0));
    float zg1 = 1.f / (1.f + __expf(-(xz0 + da_z)));
    float na0 = fmaf(rg0, gh_n, gi_n);
    float na1 = fmaf(rg1, gh_n, gi_n + da_n);
    float ee0 = __expf(-2.f * na0), ee1 = __expf(-2.f * na1);
    float n0 = (1.f - ee0) / (1.f + ee0);
    float n1 = (1.f - ee1) / (1.f + ee1);
    float h0 = (1.f - zg0) * n0 + zg0 * h_reg;
    float h1 = (1.f - zg1) * n1 + zg1 * h_reg;
    h0_reg = h0; h1_reg = h1;
    sH0me[lane] = h0; sH1me[lane] = h1;
    WAVE_FENCE();

    {
      const float* hme = isA ? sH0me : sH1me;
      float lo = hb_l;
#pragma unroll
      for (int hp = 0; hp < 32; ++hp) {
        float2 h01 = *(const float2*)&hme[2 * hp];
        float2 w = sHW2[hp * 64 + lane];
        lo = fmaf(h01.x, w.x, lo); lo = fmaf(h01.y, w.y, lo);
      }
      float pu = __expf(lo);
      float Ss = pu;
#pragma unroll
      for (int off = 32; off; off >>= 1) Ss += __shfl_xor(Ss, off, 64);
      float pr = pu / Ss;
      float ent = pr * __logf(pr + 1e-8f);
#pragma unroll
      for (int off = 32; off; off >>= 1) ent += __shfl_xor(ent, off, 64);
      if (lane == 0) {
        float be = fmaxf(-ent, 0.f);
        unsigned long long fp = (unsigned long long)(unsigned)(be * 1048576.0f + 0.5f);
        unsigned long long add = (1ull << 60) | (isA ? fp : (fp << 30));
        unsigned long long old = atomicAdd(&sBEC[t & 1], add);
        if ((old >> 60) == 7ull) {
          unsigned long long tot = old + add;
          unsigned long long e0s = tot & M30;
          unsigned long long e1s = (tot >> 30) & M30;
          unsigned long long pk = ((unsigned long long)(t + 1) << 50) | (e1s << 25) | e0s;
          __hip_atomic_store(ring + (((size_t)(t & 7)) << 8) + blockIdx.x, pk,
                             __ATOMIC_RELAXED, __HIP_MEMORY_SCOPE_AGENT);
          sBEC[t & 1] = 0ull;
        }
      }
    }

    if (wv == 0) {
      if (isRoot) root_adv(ring, mirr, sCONDW, lane, t + 1, 1, cnt, bits, cprev, rc);
      else        mirr_refresh(myMirr, sCONDW, lane, cnt, bits);
    }

    {
      float s00 = cm[0], s01 = cm[1], s10 = cm[0], s11 = cm[1];
      const float2* h02 = (const float2*)sH0me;
      const float2* h12 = (const float2*)sH1me;
#pragma unroll
      for (int hp = 0; hp < 32; ++hp) {
        float2 ha = h02[hp], hb = h12[hp];
        unsigned u0 = kp[0][hp], u1 = kp[1][hp];
        float l0 = lo16(u0), g0 = hi16(u0), l1 = lo16(u1), g1 = hi16(u1);
        s00 = fmaf(ha.x, l0, s00); s00 = fmaf(ha.y, g0, s00);
        s01 = fmaf(ha.x, l1, s01); s01 = fmaf(ha.y, g1, s01);
        s10 = fmaf(hb.x, l0, s10); s10 = fmaf(hb.y, g0, s10);
        s11 = fmaf(hb.x, l1, s11); s11 = fmaf(hb.y, g1, s11);
      }
      float e00 = __expf(s00 * SCALE_), e01 = __expf(s01 * SCALE_);
      float e10 = __expf(s10 * SCALE_), e11 = __expf(s11 * SCALE_);
      float sa = e00 + e01, sb = e10 + e11;
#pragma unroll
      for (int off = 32; off; off >>= 1) {
        sa += __shfl_xor(sa, off, 64);
        sb += __shfl_xor(sb, off, 64);
      }
      sWE[lane] = e00; sWE[64 + lane] = e01;
      sWE[128 + lane] = e10; sWE[192 + lane] = e11;
      if (lane == 0) { sSEH[half] = sa; sSEH[2 + half] = sb; }
      WAVE_FENCE();

      float al0 = 0.f, al1 = 0.f;
      const float4* wa = (const float4*)sWE;
      const float4* wb = (const float4*)(sWE + 128);
#pragma unroll
      for (int mp = 0; mp < 32; ++mp) {
        float4 qa = wa[mp], qb = wb[mp];
        unsigned u0 = vt[2 * mp], u1 = vt[2 * mp + 1];
        float v0 = lo16(u0), v1 = hi16(u0), v2 = lo16(u1), v3 = hi16(u1);
        al0 = fmaf(qa.x, v0, al0); al0 = fmaf(qa.y, v1, al0);
        al0 = fmaf(qa.z, v2, al0); al0 = fmaf(qa.w, v3, al0);
        al1 = fmaf(qb.x, v0, al1); al1 = fmaf(qb.y, v1, al1);
        al1 = fmaf(qb.z, v2, al1); al1 = fmaf(qb.w, v3, al1);
      }
      sNUM[half * 64 + lane] = al0;
      sNUM[128 + half * 64 + lane] = al1;
    }

    if (wv == 0) {
      if (isRoot) root_adv(ring, mirr, sCONDW, lane, t + 1, 1, cnt, bits, cprev, rc);
      else        mirr_refresh(myMirr, sCONDW, lane, cnt, bits);
    }
    __syncthreads();
  }

  if (wv == 0) {
    if (isRoot) {
      while (cnt < LL) {
        unsigned long long ds;
        if (!sweep_try(ring, cnt, lane, cprev, ds, SPIN_MAND)) ds = 0;
        cprev = ds > GATE_SUM; rc += cprev ? 1 : 0;
        bits = (bits << 1) | (cprev ? 1u : 0u); ++cnt;
        unsigned long long mv = ((unsigned long long)cnt << 32) | bits;
        for (int i = lane; i < 256; i += 64)
          __hip_atomic_store(mirr + (size_t)i * 8, mv,
                             __ATOMIC_RELAXED, __HIP_MEMORY_SCOPE_AGENT);
        if (lane == 0) *sCONDW = ((unsigned)cnt << 8) | (bits & 0xFFu);
      }
      if (lane == 0) out[BB * 64] = (float)rc / (float)LL;
    } else {
      int guard = SPIN_POLL;
      while (cnt < LL - 1) {
        mirr_refresh(myMirr, sCONDW, lane, cnt, bits);
        if (cnt >= LL - 1) break;
        if (--guard <= 0) break;
        __builtin_amdgcn_s_sleep(8);
      }
      if (lane == 0) *sCONDW = ((unsigned)cnt << 8) | (bits & 0xFFu);
    }
  }

  if (isA) {
    unsigned cv; int guard = SPIN_LDS;
    for (;;) {
      cv = *sCONDW;
      if ((int)(cv >> 8) >= LL - 1) break;
      if (--guard <= 0) break;
      __builtin_amdgcn_s_sleep(1);
    }
    int off = (int)(cv >> 8) - (LL - 1);
    bool c = (off >= 0 && off < 8) ? (((cv >> off) & 1u) != 0u) : false;
    const float* hf = c ? sH1me : sH0me;
    float lof = hb_l;
#pragma unroll 8
    for (int h = 0; h < 64; ++h) lof = fmaf(hf[h], head_w[lane * 64 + h], lof);
    out[(size_t)b * 64 + lane] = lof;
  }
}

// =====================================================================
extern "C" void kernel_launch(void* const* d_in, const int* in_sizes, int n_in,
                              void* d_out, int out_size, void* d_ws, size_t ws_size,
                              hipStream_t stream)
{
  (void)in_sizes; (void)n_in; (void)out_size; (void)ws_size;
  const int*   seq    = (const int*)  d_in[0];
  const float* memory = (const float*)d_in[1];
  const float* embed  = (const float*)d_in[2];
  const float* w_ih   = (const float*)d_in[3];
  const float* w_hh   = (const float*)d_in[4];
  const float* b_ih   = (const float*)d_in[5];
  const float* b_hh   = (const float*)d_in[6];
  const float* wq     = (const float*)d_in[7];
  const float* bq     = (const float*)d_in[8];
  const float* wk     = (const float*)d_in[9];
  const float* bk     = (const float*)d_in[10];
  const float* wv     = (const float*)d_in[11];
  const float* bv     = (const float*)d_in[12];
  const float* head_w = (const float*)d_in[13];
  const float* head_b = (const float*)d_in[14];
  unsigned char* ws   = (unsigned char*)d_ws;
  float* out          = (float*)d_out;

  // zero ring + mirrors + speculation flag every call (graph-safe)
  hipMemsetAsync(d_ws, 0, 32832, stream);

  hipLaunchKernelGGL(reactive_pre, dim3(1), dim3(1024), 0, stream,
                     embed, w_ih, w_hh, b_ih, wq, bq, wk, bk, head_w, ws);

  hipFuncSetAttribute((const void*)reactive_fast,
                      hipFuncAttributeMaxDynamicSharedMemorySize, FK_LDS);
  hipLaunchKernelGGL(reactive_fast, dim3(256), dim3(512), FK_LDS, stream,
                     seq, memory, wv, bv, b_hh, head_w, head_b, ws, out);

  hipFuncSetAttribute((const void*)reactive_full,
                      hipFuncAttributeMaxDynamicSharedMemorySize, LDS_BYTES);
  hipLaunchKernelGGL(reactive_full, dim3(256), dim3(512), LDS_BYTES, stream,
                     seq, memory, wv, bv, b_hh, head_w, head_b, ws, out);
}

// Round 17
// 18723.926 us; speedup vs baseline: 1.9833x; 1.9833x over previous
//
#include <hip/hip_runtime.h>
#include <stdint.h>

// Problem constants
#define HD       64
#define MM       256
#define BB       1024
#define LL       2048
#define SCALE_   0.125f
#define ETHRESH_VERIFY 2.60f       // speculation check: per-element entropy must exceed this
#define GATE_SUM (2560ull << 20)
#define M30      0x3FFFFFFFull
#define M25      0x1FFFFFFull
#define SPIN_MAND (1 << 17)
#define SPIN_POLL 8192
#define SPIN_LDS (1 << 22)

// ---------------- workspace (d_ws) layout, bytes ----------------
#define WS_RING  0           // 16384 (fallback only)
#define WS_MIRR  16384       // 16384 (fallback only)
#define WS_FLAG  32768       // u32: speculation-failed flag (zeroed each launch)
#define WS_WPA   32832       // [32 kp][3 g][64 j] u32 bf16-pairs of w_ih r-cols (24576)
#define WS_WPB   57408       // same for w_hh (24576)
#define WS_G     81984       // [64 tok][96] u32 bf16 pairs: embed@Wx^T + b_ih (24576)
#define WS_HWT2  106560      // [32 hp][64 o] float2 head_w pairs over h (16384)
#define WS_W2    122944      // [64][64] f32 wk^T@wq (16384)
#define WS_D     139328      // [64] f32 bk@wq
#define WS_E     139584      // [64] f32 bq@wk
#define WS_F     139840      // f32 bq.bk

// ---------------- shared LDS weight region ----------------
#define LD_WPA   0           // 24576
#define LD_WPB   24576       // 24576
#define LD_G     49152       // 24576
#define LD_HWT2  73728       // 16384
#define LD_DYN   90112

// fast-kernel dynamic region: 4 b * 4096
#define FDYN_STRIDE 4096
#define FD_GI    0           // 3*64 f32
#define FD_GH    768         // 3*64 f32
#define FD_HA    1536        // 64 f32 (A's h copy)
#define FD_HB    1792        // 64 f32 (B's h copy)
#define FD_NUM   2048        // 128 f32
#define FD_WEA   2560        // 128 f32
#define FD_WEB   3072        // 128 f32
#define FD_SE    3584        // 2 f32

// fallback dynamic region: 4 b * 6656 (R12 layout)
#define DYN_STRIDE 6656
#define DY_GI    0
#define DY_GH    1536
#define DY_H0A   2304
#define DY_H1A   2560
#define DY_H0B   2816
#define DY_H1B   3072
#define DY_NUM   3328
#define DY_WEA   4352
#define DY_WEB   5376
#define DY_SEH   6400
#define LD_MISC  116736

// phase-0 overlay (both kernels)
#define P0_W2P   0
#define P0_WVT2  8192
#define P0_D     16384
#define P0_E     16640
#define P0_F     16896
#define P0_MC    17408       // + wv*16640
#define MC_BYTES 16640

#define LDS_BYTES 150528

__device__ __forceinline__ unsigned bf16r(float x) {
  unsigned u = __float_as_uint(x);
  return (u + 0x7fffu + ((u >> 16) & 1u)) >> 16;
}
__device__ __forceinline__ unsigned pack2(float a, float b) {
  return bf16r(a) | (bf16r(b) << 16);
}
__device__ __forceinline__ float lo16(unsigned u) { return __uint_as_float(u << 16); }
__device__ __forceinline__ float hi16(unsigned u) { return __uint_as_float(u & 0xffff0000u); }

#define WAVE_FENCE() asm volatile("s_waitcnt lgkmcnt(0)" ::: "memory")

// =====================================================================
// P1: one-time weight preprocessing into workspace
// =====================================================================
extern "C" __global__ void reactive_pre(
    const float* __restrict__ embed, const float* __restrict__ w_ih,
    const float* __restrict__ w_hh,  const float* __restrict__ b_ih,
    const float* __restrict__ wq,    const float* __restrict__ bq,
    const float* __restrict__ wk,    const float* __restrict__ bk,
    const float* __restrict__ head_w, unsigned char* __restrict__ ws)
{
  const int tid = threadIdx.x;  // 1024 threads, 1 block

  unsigned* wpa = (unsigned*)(ws + WS_WPA);
  unsigned* wpb = (unsigned*)(ws + WS_WPB);
  for (int i = tid; i < 6144; i += 1024) {
    int q = i / 192, row = i % 192;
    wpa[i] = pack2(w_ih[row * 128 + 64 + 2 * q], w_ih[row * 128 + 64 + 2 * q + 1]);
    wpb[i] = pack2(w_hh[row * 64 + 2 * q],       w_hh[row * 64 + 2 * q + 1]);
  }
  unsigned* gp = (unsigned*)(ws + WS_G);
  for (int i = tid; i < 64 * 96; i += 1024) {
    int v = i / 96, u = i % 96;
    int j0 = 2 * u, j1 = j0 + 1;
    float g0 = b_ih[j0], g1 = b_ih[j1];
    for (int h = 0; h < 64; ++h) {
      float ev = embed[v * 64 + h];
      g0 = fmaf(ev, w_ih[j0 * 128 + h], g0);
      g1 = fmaf(ev, w_ih[j1 * 128 + h], g1);
    }
    gp[i] = pack2(g0, g1);
  }
  float2* hwt2 = (float2*)(ws + WS_HWT2);
  for (int i = tid; i < 2048; i += 1024) {
    int hp = i >> 6, o = i & 63;
    hwt2[i] = make_float2(head_w[o * 64 + 2 * hp], head_w[o * 64 + 2 * hp + 1]);
  }
  float* w2 = (float*)(ws + WS_W2);
  for (int i = tid; i < 4096; i += 1024) {
    int h2 = i >> 6, h = i & 63;
    float a = 0.f;
    for (int o = 0; o < 64; ++o) a = fmaf(wk[o * 64 + h2], wq[o * 64 + h], a);
    w2[i] = a;
  }
  if (tid < 64) {
    float a = 0.f, b2 = 0.f;
    for (int o = 0; o < 64; ++o) a  = fmaf(bk[o], wq[o * 64 + tid], a);
    for (int o = 0; o < 64; ++o) b2 = fmaf(bq[o], wk[o * 64 + tid], b2);
    ((float*)(ws + WS_D))[tid] = a;
    ((float*)(ws + WS_E))[tid] = b2;
  }
  if (tid == 0) {
    float a = 0.f;
    for (int o = 0; o < 64; ++o) a = fmaf(bq[o], bk[o], a);
    *(float*)(ws + WS_F) = a;
  }
}

// =====================================================================
// FAST kernel: speculate cond(t)=TRUE for all t (provable from weight
// magnitudes: per-element softmax entropy >= ln64 - logit_spread > 2.5).
// Zero inter-block communication. Each A-wave VERIFIES its own entropy
// > 2.60 every step; any violation sets ws flag -> fallback kernel runs.
// 256 blocks x 512 threads (8 waves = 4 b's x {A,B}), 2 barriers/step.
// =====================================================================
extern "C" __global__ void __launch_bounds__(512, 2)
reactive_fast(const int* __restrict__ seq, const float* __restrict__ memory,
              const float* __restrict__ wvp, const float* __restrict__ bvp,
              const float* __restrict__ b_hh, const float* __restrict__ head_w,
              const float* __restrict__ head_b, unsigned char* __restrict__ ws,
              float* __restrict__ out)
{
  extern __shared__ __align__(16) unsigned char lds[];
  const int tid     = threadIdx.x;
  const int wv      = tid >> 6;
  const int lane    = tid & 63;
  const int half    = wv >> 2;       // 0 = A, 1 = B
  const int b_local = wv & 3;
  const int b       = (int)blockIdx.x * 4 + b_local;
  const bool isA    = (half == 0);

  unsigned kp[2][32];   // K' bf16 pairs for m = half*128 + g*64 + lane
  unsigned vt[64];      // V bf16 pairs over this half's 128 m-rows
  float    cm[2];

  // ---------------- phase 0: per-(b,half) K', V^T, c into registers ----------------
  {
    unsigned* w2p  = (unsigned*)(lds + P0_W2P);
    unsigned* wvt2 = (unsigned*)(lds + P0_WVT2);
    float* pD = (float*)(lds + P0_D);
    float* pE = (float*)(lds + P0_E);
    float* pF = (float*)(lds + P0_F);
    const float* wsW2 = (const float*)(ws + WS_W2);
    for (int i = tid; i < 2048; i += 512) {
      int h2 = i >> 5, hp = i & 31;
      w2p[i] = pack2(wsW2[h2 * 64 + 2 * hp], wsW2[h2 * 64 + 2 * hp + 1]);
    }
    for (int i = tid; i < 2048; i += 512) {
      int h2p = i >> 6, l = i & 63;
      wvt2[i] = pack2(wvp[l * 64 + 2 * h2p], wvp[l * 64 + 2 * h2p + 1]);
    }
    if (tid < 64) { pD[tid] = ((const float*)(ws + WS_D))[tid];
                    pE[tid] = ((const float*)(ws + WS_E))[tid]; }
    if (tid == 0) pF[0] = *(const float*)(ws + WS_F);
    __syncthreads();

    float* mc = (float*)(lds + P0_MC + wv * MC_BYTES);   // [64][65]
    const float bvl   = bvp[lane];
    const float fscal = pF[0];
    const float* memb = memory + ((size_t)b * MM + (size_t)half * 128) * HD;

    for (int g = 0; g < 2; ++g) {
      WAVE_FENCE();
#pragma unroll 4
      for (int r = 0; r < 64; ++r)
        mc[r * 65 + lane] = memb[(size_t)(g * 64 + r) * HD + lane];
      WAVE_FENCE();

      float acc[64];
#pragma unroll
      for (int h = 0; h < 64; ++h) acc[h] = pD[h];
      float cacc = fscal;
      for (int h2 = 0; h2 < 64; ++h2) {
        float mv = mc[lane * 65 + h2];
        cacc = fmaf(mv, pE[h2], cacc);
        const unsigned* wrow = w2p + h2 * 32;
#pragma unroll
        for (int hp = 0; hp < 32; ++hp) {
          unsigned u = wrow[hp];
          acc[2 * hp]     = fmaf(mv, lo16(u), acc[2 * hp]);
          acc[2 * hp + 1] = fmaf(mv, hi16(u), acc[2 * hp + 1]);
        }
      }
      cm[g] = cacc;
#pragma unroll
      for (int u = 0; u < 32; ++u) kp[g][u] = pack2(acc[2 * u], acc[2 * u + 1]);

      for (int rp = 0; rp < 32; ++rp) {
        float a0 = bvl, a1 = bvl;
#pragma unroll
        for (int hq = 0; hq < 32; ++hq) {
          unsigned w = wvt2[hq * 64 + lane];
          float wl = lo16(w), wh = hi16(w);
          const float2 m0 = *(const float2*)&mc[(2 * rp) * 65 + 2 * hq];
          const float2 m1 = *(const float2*)&mc[(2 * rp + 1) * 65 + 2 * hq];
          a0 = fmaf(m0.x, wl, a0); a0 = fmaf(m0.y, wh, a0);
          a1 = fmaf(m1.x, wl, a1); a1 = fmaf(m1.y, wh, a1);
        }
        vt[32 * g + rp] = pack2(a0, a1);
      }
    }
    __syncthreads();
  }

  // ---------------- stage weights; init dynamic region ----------------
  {
    const float4* s1 = (const float4*)(ws + WS_WPA);   float4* d1 = (float4*)(lds + LD_WPA);
    for (int i = tid; i < 1536; i += 512) d1[i] = s1[i];
    const float4* s2 = (const float4*)(ws + WS_WPB);   float4* d2 = (float4*)(lds + LD_WPB);
    for (int i = tid; i < 1536; i += 512) d2[i] = s2[i];
    const float4* s3 = (const float4*)(ws + WS_G);     float4* d3 = (float4*)(lds + LD_G);
    for (int i = tid; i < 1536; i += 512) d3[i] = s3[i];
    const float4* s4 = (const float4*)(ws + WS_HWT2);  float4* d4 = (float4*)(lds + LD_HWT2);
    for (int i = tid; i < 1024; i += 512) d4[i] = s4[i];
    float* dz = (float*)(lds + LD_DYN);
    for (int i = tid; i < 4 * FDYN_STRIDE / 4; i += 512) dz[i] = 0.f;
    __syncthreads();
    if (tid < 4) {
      float* se = (float*)(lds + LD_DYN + tid * FDYN_STRIDE + FD_SE);
      se[0] = 1.f; se[1] = 1.f;
    }
    __syncthreads();
  }

  const unsigned* sWPA = (const unsigned*)(lds + LD_WPA);
  const unsigned* sWPB = (const unsigned*)(lds + LD_WPB);
  const unsigned* sG   = (const unsigned*)(lds + LD_G);
  const float2*   sHW2 = (const float2*)(lds + LD_HWT2);
  unsigned char* dynp = lds + LD_DYN + b_local * FDYN_STRIDE;
  float* sGI  = (float*)(dynp + FD_GI);
  float* sGH  = (float*)(dynp + FD_GH);
  float* sHme = (float*)(dynp + (isA ? FD_HA : FD_HB));
  float* sNUM = (float*)(dynp + FD_NUM);
  float* sWE  = (float*)(dynp + (isA ? FD_WEA : FD_WEB));
  float* sSE  = (float*)(dynp + FD_SE);
  unsigned* flag = (unsigned*)(ws + WS_FLAG);
  const int* seqb = seq + (size_t)b * LL;

  float h_reg = 0.f;
  float bh_r = 0.f, bh_z = 0.f, bh_n = 0.f;
  if (!isA) { bh_r = b_hh[lane]; bh_z = b_hh[64 + lane]; bh_n = b_hh[128 + lane]; }
  const float hb_l = head_b[lane];
  float own_r = 0.f, own_z = 0.f, own_n = 0.f;
  bool specOK = true;

  for (int t = 0; t < LL; ++t) {
    // ---- phase 1: A computes gi = G[token] + (num@Wr)/Se; B computes gh ----
    if (isA) {
      float Se = sSE[0] + sSE[1];
      float rcpSe = 1.0f / Se;
      int token = seqb[t];
      float sr = 0.f, sz = 0.f, sn = 0.f;
#pragma unroll
      for (int q = 0; q < 32; ++q) {
        float2 n0 = *(const float2*)&sNUM[2 * q];
        float2 n1 = *(const float2*)&sNUM[64 + 2 * q];
        float a0 = n0.x + n1.x, a1 = n0.y + n1.y;
        unsigned ur = sWPA[q * 192 + lane];
        unsigned uz = sWPA[q * 192 + 64 + lane];
        unsigned un = sWPA[q * 192 + 128 + lane];
        sr = fmaf(a0, lo16(ur), sr); sr = fmaf(a1, hi16(ur), sr);
        sz = fmaf(a0, lo16(uz), sz); sz = fmaf(a1, hi16(uz), sz);
        sn = fmaf(a0, lo16(un), sn); sn = fmaf(a1, hi16(un), sn);
      }
      unsigned gp0 = sG[token * 96 +      (lane >> 1)];
      unsigned gp1 = sG[token * 96 + 32 + (lane >> 1)];
      unsigned gp2 = sG[token * 96 + 64 + (lane >> 1)];
      bool oddl = (lane & 1);
      float g_r = oddl ? hi16(gp0) : lo16(gp0);
      float g_z = oddl ? hi16(gp1) : lo16(gp1);
      float g_n = oddl ? hi16(gp2) : lo16(gp2);
      own_r = fmaf(rcpSe, sr, g_r);
      own_z = fmaf(rcpSe, sz, g_z);
      own_n = fmaf(rcpSe, sn, g_n);
      sGI[lane] = own_r; sGI[64 + lane] = own_z; sGI[128 + lane] = own_n;
    } else {
      float hr = bh_r, hz = bh_z, hn = bh_n;
#pragma unroll
      for (int q = 0; q < 32; ++q) {
        float2 h01 = *(const float2*)&sHme[2 * q];   // own copy of h(t-1)
        unsigned ur = sWPB[q * 192 + lane];
        unsigned uz = sWPB[q * 192 + 64 + lane];
        unsigned un = sWPB[q * 192 + 128 + lane];
        hr = fmaf(h01.x, lo16(ur), hr); hr = fmaf(h01.y, hi16(ur), hr);
        hz = fmaf(h01.x, lo16(uz), hz); hz = fmaf(h01.y, hi16(uz), hz);
        hn = fmaf(h01.x, lo16(un), hn); hn = fmaf(h01.y, hi16(un), hn);
      }
      own_r = hr; own_z = hz; own_n = hn;
      sGH[lane] = hr; sGH[64 + lane] = hz; sGH[128 + lane] = hn;
    }
    __syncthreads();   // X

    // ---- phase 2: gates (redundant & bit-identical on A and B) ----
    float o1, o2, o3;
    if (isA) { o1 = sGH[lane]; o2 = sGH[64 + lane]; o3 = sGH[128 + lane]; }
    else     { o1 = sGI[lane]; o2 = sGI[64 + lane]; o3 = sGI[128 + lane]; }
    float xr = own_r + o1;
    float xz = own_z + o2;
    float gin_v = isA ? own_n : o3;
    float ghn_v = isA ? o3 : own_n;
    float rg = 1.f / (1.f + __expf(-xr));
    float zg = 1.f / (1.f + __expf(-xz));
    float narg = fmaf(rg, ghn_v, gin_v);
    float eee = __expf(-2.f * narg);
    float ng = (1.f - eee) / (1.f + eee);
    float h_new = (1.f - zg) * ng + zg * h_reg;
    sHme[lane] = h_new;   // own wave-private copy
    WAVE_FENCE();

    // ---- phase 3 (A only): VERIFY entropy > 2.60 (=> grid mean > 2.5) ----
    if (isA) {
      float lo = hb_l;
#pragma unroll
      for (int hp = 0; hp < 32; ++hp) {
        float2 h01 = *(const float2*)&sHme[2 * hp];
        float2 w = sHW2[hp * 64 + lane];
        lo = fmaf(h01.x, w.x, lo); lo = fmaf(h01.y, w.y, lo);
      }
      float pu = __expf(lo);
      float Ss = pu;
#pragma unroll
      for (int off = 32; off; off >>= 1) Ss += __shfl_xor(Ss, off, 64);
      float pr = pu / Ss;
      float ent = pr * __logf(pr + 1e-8f);
#pragma unroll
      for (int off = 32; off; off >>= 1) ent += __shfl_xor(ent, off, 64);
      if (!(-ent > ETHRESH_VERIFY)) specOK = false;
    }

    // ---- phase 5: attention on h_new (own half; no max-sub, bounded) ----
    {
      float s0 = cm[0], s1 = cm[1];
      const float2* h2p = (const float2*)sHme;
#pragma unroll
      for (int hp = 0; hp < 32; ++hp) {
        float2 hv = h2p[hp];
        unsigned u0 = kp[0][hp], u1 = kp[1][hp];
        s0 = fmaf(hv.x, lo16(u0), s0); s0 = fmaf(hv.y, hi16(u0), s0);
        s1 = fmaf(hv.x, lo16(u1), s1); s1 = fmaf(hv.y, hi16(u1), s1);
      }
      float e0 = __expf(s0 * SCALE_), e1 = __expf(s1 * SCALE_);
      float seh = e0 + e1;
#pragma unroll
      for (int off = 32; off; off >>= 1) seh += __shfl_xor(seh, off, 64);
      sWE[lane] = e0; sWE[64 + lane] = e1;
      if (lane == 0) sSE[half] = seh;
      WAVE_FENCE();

      float al = 0.f;
      const float4* w4 = (const float4*)sWE;
#pragma unroll
      for (int mp = 0; mp < 32; ++mp) {
        float4 wq4 = w4[mp];
        unsigned u0 = vt[2 * mp], u1 = vt[2 * mp + 1];
        al = fmaf(wq4.x, lo16(u0), al);
        al = fmaf(wq4.y, hi16(u0), al);
        al = fmaf(wq4.z, lo16(u1), al);
        al = fmaf(wq4.w, hi16(u1), al);
      }
      sNUM[half * 64 + lane] = al;
    }
    h_reg = h_new;
    __syncthreads();   // W
  }

  // ---- speculation failure -> raise flag (fallback kernel takes over) ----
  if (isA && !specOK && lane == 0)
    __hip_atomic_store(flag, 1u, __ATOMIC_RELAXED, __HIP_MEMORY_SCOPE_AGENT);

  // ---- final logits with f32 head weights ----
  if (isA) {
    float lof = hb_l;
#pragma unroll 8
    for (int h = 0; h < 64; ++h) lof = fmaf(sHme[h], head_w[lane * 64 + h], lof);
    out[(size_t)b * 64 + lane] = lof;
  }
  if (blockIdx.x == 0 && tid == 0) out[BB * 64] = 1.0f;  // all cond true
}

// =====================================================================
// FALLBACK: full grid-consensus kernel (proven). Runs only if the
// speculation flag is set; otherwise exits immediately.
// =====================================================================
__device__ __forceinline__ int sweep_try(const unsigned long long* ring, int s, int lane,
                                         bool cprev, unsigned long long& dsum, int rounds) {
  const unsigned long long* rb = ring + (((size_t)(s & 7)) << 8) + 4 * lane;
  const unsigned long long want = (unsigned long long)(s + 1);
  unsigned long long v0, v1, v2, v3;
  int r = 0;
  for (;;) {
    v0 = __hip_atomic_load(rb + 0, __ATOMIC_RELAXED, __HIP_MEMORY_SCOPE_AGENT);
    v1 = __hip_atomic_load(rb + 1, __ATOMIC_RELAXED, __HIP_MEMORY_SCOPE_AGENT);
    v2 = __hip_atomic_load(rb + 2, __ATOMIC_RELAXED, __HIP_MEMORY_SCOPE_AGENT);
    v3 = __hip_atomic_load(rb + 3, __ATOMIC_RELAXED, __HIP_MEMORY_SCOPE_AGENT);
    bool ok = ((v0 >> 50) == want) && ((v1 >> 50) == want) &&
              ((v2 >> 50) == want) && ((v3 >> 50) == want);
    if (__all(ok)) break;
    if (++r >= rounds) return 0;
    __builtin_amdgcn_s_sleep(1);
  }
  unsigned long long d;
  if (cprev) d = ((v0 >> 25) & M25) + ((v1 >> 25) & M25) +
                 ((v2 >> 25) & M25) + ((v3 >> 25) & M25);
  else       d = (v0 & M25) + (v1 & M25) + (v2 & M25) + (v3 & M25);
#pragma unroll
  for (int off = 32; off; off >>= 1) d += __shfl_xor(d, off, 64);
  dsum = d;
  return 1;
}

__device__ __forceinline__ void root_adv(unsigned long long* ring, unsigned long long* mirr,
                                         volatile unsigned* sCONDW, int lane, int target,
                                         int rounds, int& cnt, unsigned& bits,
                                         bool& cprev, int& rc) {
  while (cnt < target) {
    unsigned long long ds;
    if (!sweep_try(ring, cnt, lane, cprev, ds, rounds)) break;
    cprev = ds > GATE_SUM; rc += cprev ? 1 : 0;
    bits = (bits << 1) | (cprev ? 1u : 0u); ++cnt;
    unsigned long long mv = ((unsigned long long)cnt << 32) | bits;
    for (int i = lane; i < 256; i += 64)
      __hip_atomic_store(mirr + (size_t)i * 8, mv,
                         __ATOMIC_RELAXED, __HIP_MEMORY_SCOPE_AGENT);
    if (lane == 0) *sCONDW = ((unsigned)cnt << 8) | (bits & 0xFFu);
  }
}

__device__ __forceinline__ void mirr_refresh(const unsigned long long* myMirr,
                                             volatile unsigned* sCONDW, int lane,
                                             int& cnt, unsigned& bits) {
  unsigned hi = 0, lo = 0;
  if (lane == 0) {
    unsigned long long v = __hip_atomic_load(myMirr, __ATOMIC_RELAXED,
                                             __HIP_MEMORY_SCOPE_AGENT);
    hi = (unsigned)(v >> 32); lo = (unsigned)v;
  }
  hi = (unsigned)__shfl((int)hi, 0, 64);
  lo = (unsigned)__shfl((int)lo, 0, 64);
  if ((int)hi > cnt) {
    cnt = (int)hi; bits = lo;
    if (lane == 0) *sCONDW = ((unsigned)cnt << 8) | (bits & 0xFFu);
  }
}

extern "C" __global__ void __launch_bounds__(512, 2)
reactive_full(const int* __restrict__ seq, const float* __restrict__ memory,
              const float* __restrict__ wvp, const float* __restrict__ bvp,
              const float* __restrict__ b_hh, const float* __restrict__ head_w,
              const float* __restrict__ head_b, unsigned char* __restrict__ ws,
              float* __restrict__ out)
{
  if (__hip_atomic_load((unsigned*)(ws + WS_FLAG), __ATOMIC_RELAXED,
                        __HIP_MEMORY_SCOPE_AGENT) == 0u)
    return;   // speculation held; fast kernel's output stands

  extern __shared__ __align__(16) unsigned char lds[];
  const int tid     = threadIdx.x;
  const int wv      = tid >> 6;
  const int lane    = tid & 63;
  const int half    = wv >> 2;
  const int b_local = wv & 3;
  const int b       = (int)blockIdx.x * 4 + b_local;
  const bool isA    = (half == 0);
  const bool isRoot = (blockIdx.x == 0);

  unsigned kp[2][32];
  unsigned vt[64];
  float    cm[2];

  {
    unsigned* w2p  = (unsigned*)(lds + P0_W2P);
    unsigned* wvt2 = (unsigned*)(lds + P0_WVT2);
    float* pD = (float*)(lds + P0_D);
    float* pE = (float*)(lds + P0_E);
    float* pF = (float*)(lds + P0_F);
    const float* wsW2 = (const float*)(ws + WS_W2);
    for (int i = tid; i < 2048; i += 512) {
      int h2 = i >> 5, hp = i & 31;
      w2p[i] = pack2(wsW2[h2 * 64 + 2 * hp], wsW2[h2 * 64 + 2 * hp + 1]);
    }
    for (int i = tid; i < 2048; i += 512) {
      int h2p = i >> 6, l = i & 63;
      wvt2[i] = pack2(wvp[l * 64 + 2 * h2p], wvp[l * 64 + 2 * h2p + 1]);
    }
    if (tid < 64) { pD[tid] = ((const float*)(ws + WS_D))[tid];
                    pE[tid] = ((const float*)(ws + WS_E))[tid]; }
    if (tid == 0) pF[0] = *(const float*)(ws + WS_F);
    __syncthreads();

    float* mc = (float*)(lds + P0_MC + wv * MC_BYTES);
    const float bvl   = bvp[lane];
    const float fscal = pF[0];
    const float* memb = memory + ((size_t)b * MM + (size_t)half * 128) * HD;

    for (int g = 0; g < 2; ++g) {
      WAVE_FENCE();
#pragma unroll 4
      for (int r = 0; r < 64; ++r)
        mc[r * 65 + lane] = memb[(size_t)(g * 64 + r) * HD + lane];
      WAVE_FENCE();

      float acc[64];
#pragma unroll
      for (int h = 0; h < 64; ++h) acc[h] = pD[h];
      float cacc = fscal;
      for (int h2 = 0; h2 < 64; ++h2) {
        float mv = mc[lane * 65 + h2];
        cacc = fmaf(mv, pE[h2], cacc);
        const unsigned* wrow = w2p + h2 * 32;
#pragma unroll
        for (int hp = 0; hp < 32; ++hp) {
          unsigned u = wrow[hp];
          acc[2 * hp]     = fmaf(mv, lo16(u), acc[2 * hp]);
          acc[2 * hp + 1] = fmaf(mv, hi16(u), acc[2 * hp + 1]);
        }
      }
      cm[g] = cacc;
#pragma unroll
      for (int u = 0; u < 32; ++u) kp[g][u] = pack2(acc[2 * u], acc[2 * u + 1]);

      for (int rp = 0; rp < 32; ++rp) {
        float a0 = bvl, a1 = bvl;
#pragma unroll
        for (int hq = 0; hq < 32; ++hq) {
          unsigned w = wvt2[hq * 64 + lane];
          float wl = lo16(w), wh = hi16(w);
          const float2 m0 = *(const float2*)&mc[(2 * rp) * 65 + 2 * hq];
          const float2 m1 = *(const float2*)&mc[(2 * rp + 1) * 65 + 2 * hq];
          a0 = fmaf(m0.x, wl, a0); a0 = fmaf(m0.y, wh, a0);
          a1 = fmaf(m1.x, wl, a1); a1 = fmaf(m1.y, wh, a1);
        }
        vt[32 * g + rp] = pack2(a0, a1);
      }
    }
    __syncthreads();
  }

  {
    const float4* s1 = (const float4*)(ws + WS_WPA);   float4* d1 = (float4*)(lds + LD_WPA);
    for (int i = tid; i < 1536; i += 512) d1[i] = s1[i];
    const float4* s2 = (const float4*)(ws + WS_WPB);   float4* d2 = (float4*)(lds + LD_WPB);
    for (int i = tid; i < 1536; i += 512) d2[i] = s2[i];
    const float4* s3 = (const float4*)(ws + WS_G);     float4* d3 = (float4*)(lds + LD_G);
    for (int i = tid; i < 1536; i += 512) d3[i] = s3[i];
    const float4* s4 = (const float4*)(ws + WS_HWT2);  float4* d4 = (float4*)(lds + LD_HWT2);
    for (int i = tid; i < 1024; i += 512) d4[i] = s4[i];
    float* dz = (float*)(lds + LD_DYN);
    for (int i = tid; i < 4 * DYN_STRIDE / 4; i += 512) dz[i] = 0.f;
    if (tid < 5) ((unsigned*)(lds + LD_MISC))[tid] = 0u;
    __syncthreads();
    if (tid < 4) {
      float* se = (float*)(lds + LD_DYN + tid * DYN_STRIDE + DY_SEH);
      se[0] = 1.f; se[1] = 1.f; se[2] = 1.f; se[3] = 1.f;
    }
    __syncthreads();
  }

  const unsigned* sWPA = (const unsigned*)(lds + LD_WPA);
  const unsigned* sWPB = (const unsigned*)(lds + LD_WPB);
  const unsigned* sG   = (const unsigned*)(lds + LD_G);
  const float2*   sHW2 = (const float2*)(lds + LD_HWT2);
  unsigned char* dynp = lds + LD_DYN + b_local * DYN_STRIDE;
  float* sGI   = (float*)(dynp + DY_GI);
  float* sGH   = (float*)(dynp + DY_GH);
  float* sH0me = (float*)(dynp + (isA ? DY_H0A : DY_H0B));
  float* sH1me = (float*)(dynp + (isA ? DY_H1A : DY_H1B));
  float* sNUM  = (float*)(dynp + DY_NUM);
  float* sWE   = (float*)(dynp + (isA ? DY_WEA : DY_WEB));
  float* sSEH  = (float*)(dynp + DY_SEH);
  unsigned long long* sBEC = (unsigned long long*)(lds + LD_MISC);
  volatile unsigned* sCONDW = (volatile unsigned*)(lds + LD_MISC + 16);
  unsigned long long* ring = (unsigned long long*)(ws + WS_RING);
  unsigned long long* mirr = (unsigned long long*)(ws + WS_MIRR);
  unsigned long long* myMirr = mirr + (size_t)blockIdx.x * 8;
  const int* seqb = seq + (size_t)b * LL;

  float h0_reg = 0.f, h1_reg = 0.f, h_reg = 0.f;
  int cnt = 0, rc = 0;
  unsigned bits = 0;
  bool cprev = false;

  float bh_r = 0.f, bh_z = 0.f, bh_n = 0.f;
  if (!isA) { bh_r = b_hh[lane]; bh_z = b_hh[64 + lane]; bh_n = b_hh[128 + lane]; }
  const float hb_l = head_b[lane];

  float a_gr = 0.f, a_gz = 0.f, a_gn = 0.f, a_dr = 0.f, a_dz = 0.f, a_dn = 0.f;
  float b_hr = 0.f, b_hz = 0.f, b_hn = 0.f;

  for (int t = 0; t < LL; ++t) {
    bool c2 = false;
    if (wv == 0) {
      if (isRoot) {
        while (cnt < t - 1) {
          unsigned long long ds;
          if (!sweep_try(ring, cnt, lane, cprev, ds, SPIN_MAND)) ds = 0;
          cprev = ds > GATE_SUM; rc += cprev ? 1 : 0;
          bits = (bits << 1) | (cprev ? 1u : 0u); ++cnt;
          unsigned long long mv = ((unsigned long long)cnt << 32) | bits;
          for (int i = lane; i < 256; i += 64)
            __hip_atomic_store(mirr + (size_t)i * 8, mv,
                               __ATOMIC_RELAXED, __HIP_MEMORY_SCOPE_AGENT);
          if (lane == 0) *sCONDW = ((unsigned)cnt << 8) | (bits & 0xFFu);
        }
        root_adv(ring, mirr, sCONDW, lane, t, 2, cnt, bits, cprev, rc);
        if (t >= 2) {
          int off = cnt - (t - 1);
          c2 = ((bits >> off) & 1u) != 0u;
        }
      } else if (t >= 2) {
        int guard = SPIN_POLL;
        for (;;) {
          mirr_refresh(myMirr, sCONDW, lane, cnt, bits);
          if (cnt >= t - 1) break;
          if (--guard <= 0) break;
          __builtin_amdgcn_s_sleep(8);
        }
        int off = cnt - (t - 1);
        c2 = (off >= 0 && off < 8) ? (((bits >> off) & 1u) != 0u) : false;
      }
    } else if (t >= 2) {
      unsigned cv; int guard = SPIN_LDS;
      for (;;) {
        cv = *sCONDW;
        if ((int)(cv >> 8) >= t - 1) break;
        if (--guard <= 0) break;
        __builtin_amdgcn_s_sleep(0);
      }
      int off = (int)(cv >> 8) - (t - 1);
      c2 = (off >= 0 && off < 8) ? (((cv >> off) & 1u) != 0u) : false;
    }
    h_reg = c2 ? h1_reg : h0_reg;

    if (isA) {
      float Se = sSEH[c2 ? 2 : 0] + sSEH[c2 ? 3 : 1];
      float rcpSe = 1.0f / Se;
      const float* nm = sNUM + (c2 ? 128 : 0);
      int token = seqb[t];
      float sr = 0.f, sz = 0.f, sn = 0.f;
#pragma unroll
      for (int q = 0; q < 32; ++q) {
        float2 n0 = *(const float2*)&nm[2 * q];
        float2 n1 = *(const float2*)&nm[64 + 2 * q];
        float a0 = n0.x + n1.x, a1 = n0.y + n1.y;
        unsigned ur = sWPA[q * 192 + lane];
        unsigned uz = sWPA[q * 192 + 64 + lane];
        unsigned un = sWPA[q * 192 + 128 + lane];
        sr = fmaf(a0, lo16(ur), sr); sr = fmaf(a1, hi16(ur), sr);
        sz = fmaf(a0, lo16(uz), sz); sz = fmaf(a1, hi16(uz), sz);
        sn = fmaf(a0, lo16(un), sn); sn = fmaf(a1, hi16(un), sn);
      }
      unsigned gp0 = sG[token * 96 +      (lane >> 1)];
      unsigned gp1 = sG[token * 96 + 32 + (lane >> 1)];
      unsigned gp2 = sG[token * 96 + 64 + (lane >> 1)];
      bool oddl = (lane & 1);
      a_gr = oddl ? hi16(gp0) : lo16(gp0);
      a_gz = oddl ? hi16(gp1) : lo16(gp1);
      a_gn = oddl ? hi16(gp2) : lo16(gp2);
      a_dr = rcpSe * sr; a_dz = rcpSe * sz; a_dn = rcpSe * sn;
      sGI[lane] = a_gr;        sGI[64 + lane] = a_gz;  sGI[128 + lane] = a_gn;
      sGI[192 + lane] = a_dr;  sGI[256 + lane] = a_dz; sGI[320 + lane] = a_dn;
    } else {
      const float* hprev = c2 ? sH1me : sH0me;
      float hr = bh_r, hz = bh_z, hn = bh_n;
#pragma unroll
      for (int q = 0; q < 32; ++q) {
        float2 h01 = *(const float2*)&hprev[2 * q];
        unsigned ur = sWPB[q * 192 + lane];
        unsigned uz = sWPB[q * 192 + 64 + lane];
        unsigned un = sWPB[q * 192 + 128 + lane];
        hr = fmaf(h01.x, lo16(ur), hr); hr = fmaf(h01.y, hi16(ur), hr);
        hz = fmaf(h01.x, lo16(uz), hz); hz = fmaf(h01.y, hi16(uz), hz);
        hn = fmaf(h01.x, lo16(un), hn); hn = fmaf(h01.y, hi16(un), hn);
      }
      b_hr = hr; b_hz = hz; b_hn = hn;
      sGH[lane] = hr; sGH[64 + lane] = hz; sGH[128 + lane] = hn;
    }
    __syncthreads();

    float gi_r, gi_z, gi_n, da_r, da_z, da_n, gh_r, gh_z, gh_n;
    if (isA) {
      gh_r = sGH[lane]; gh_z = sGH[64 + lane]; gh_n = sGH[128 + lane];
      gi_r = a_gr; gi_z = a_gz; gi_n = a_gn; da_r = a_dr; da_z = a_dz; da_n = a_dn;
    } else {
      gi_r = sGI[lane];       gi_z = sGI[64 + lane];  gi_n = sGI[128 + lane];
      da_r = sGI[192 + lane]; da_z = sGI[256 + lane]; da_n = sGI[320 + lane];
      gh_r = b_hr; gh_z = b_hz; gh_n = b_hn;
    }
    float xr0 = gi_r + gh_r, xz0 = gi_z + gh_z;
    float rg0 = 1.f / (1.f + __expf(-xr0));
    float rg1 = 1.f / (1.f + __expf(-(xr0 + da_r)));
    float zg0 = 1.f / (1.f + __expf(-xz0));
    float zg1 = 1.f / (1.f + __expf(-(xz0 + da_z)));
    float na0 = fmaf(rg0, gh_n, gi_n);
    float na1 = fmaf(rg1, gh_n, gi_n + da_n);
    float ee0 = __expf(-2.f * na0), ee1 = __expf(-2.f * na1);
    float n0 = (1.f - ee0) / (1.f + ee0);
    float n1 = (1.f - ee1) / (1.f + ee1);
    float h0 = (1.f - zg0) * n0 + zg0 * h_reg;
    float h1 = (1.f - zg1) * n1 + zg1 * h_reg;
    h0_reg = h0; h1_reg = h1;
    sH0me[lane] = h0; sH1me[lane] = h1;
    WAVE_FENCE();

    {
      const float* hme = isA ? sH0me : sH1me;
      float lo = hb_l;
#pragma unroll
      for (int hp = 0; hp < 32; ++hp) {
        float2 h01 = *(const float2*)&hme[2 * hp];
        float2 w = sHW2[hp * 64 + lane];
        lo = fmaf(h01.x, w.x, lo); lo = fmaf(h01.y, w.y, lo);
      }
      float pu = __expf(lo);
      float Ss = pu;
#pragma unroll
      for (int off = 32; off; off >>= 1) Ss += __shfl_xor(Ss, off, 64);
      float pr = pu / Ss;
      float ent = pr * __logf(pr + 1e-8f);
#pragma unroll
      for (int off = 32; off; off >>= 1) ent += __shfl_xor(ent, off, 64);
      if (lane == 0) {
        float be = fmaxf(-ent, 0.f);
        unsigned long long fp = (unsigned long long)(unsigned)(be * 1048576.0f + 0.5f);
        unsigned long long add = (1ull << 60) | (isA ? fp : (fp << 30));
        unsigned long long old = atomicAdd(&sBEC[t & 1], add);
        if ((old >> 60) == 7ull) {
          unsigned long long tot = old + add;
          unsigned long long e0s = tot & M30;
          unsigned long long e1s = (tot >> 30) & M30;
          unsigned long long pk = ((unsigned long long)(t + 1) << 50) | (e1s << 25) | e0s;
          __hip_atomic_store(ring + (((size_t)(t & 7)) << 8) + blockIdx.x, pk,
                             __ATOMIC_RELAXED, __HIP_MEMORY_SCOPE_AGENT);
          sBEC[t & 1] = 0ull;
        }
      }
    }

    if (wv == 0) {
      if (isRoot) root_adv(ring, mirr, sCONDW, lane, t + 1, 1, cnt, bits, cprev, rc);
      else        mirr_refresh(myMirr, sCONDW, lane, cnt, bits);
    }

    {
      float s00 = cm[0], s01 = cm[1], s10 = cm[0], s11 = cm[1];
      const float2* h02 = (const float2*)sH0me;
      const float2* h12 = (const float2*)sH1me;
#pragma unroll
      for (int hp = 0; hp < 32; ++hp) {
        float2 ha = h02[hp], hb = h12[hp];
        unsigned u0 = kp[0][hp], u1 = kp[1][hp];
        float l0 = lo16(u0), g0 = hi16(u0), l1 = lo16(u1), g1 = hi16(u1);
        s00 = fmaf(ha.x, l0, s00); s00 = fmaf(ha.y, g0, s00);
        s01 = fmaf(ha.x, l1, s01); s01 = fmaf(ha.y, g1, s01);
        s10 = fmaf(hb.x, l0, s10); s10 = fmaf(hb.y, g0, s10);
        s11 = fmaf(hb.x, l1, s11); s11 = fmaf(hb.y, g1, s11);
      }
      float e00 = __expf(s00 * SCALE_), e01 = __expf(s01 * SCALE_);
      float e10 = __expf(s10 * SCALE_), e11 = __expf(s11 * SCALE_);
      float sa = e00 + e01, sb = e10 + e11;
#pragma unroll
      for (int off = 32; off; off >>= 1) {
        sa += __shfl_xor(sa, off, 64);
        sb += __shfl_xor(sb, off, 64);
      }
      sWE[lane] = e00; sWE[64 + lane] = e01;
      sWE[128 + lane] = e10; sWE[192 + lane] = e11;
      if (lane == 0) { sSEH[half] = sa; sSEH[2 + half] = sb; }
      WAVE_FENCE();

      float al0 = 0.f, al1 = 0.f;
      const float4* wa = (const float4*)sWE;
      const float4* wb = (const float4*)(sWE + 128);
#pragma unroll
      for (int mp = 0; mp < 32; ++mp) {
        float4 qa = wa[mp], qb = wb[mp];
        unsigned u0 = vt[2 * mp], u1 = vt[2 * mp + 1];
        float v0 = lo16(u0), v1 = hi16(u0), v2 = lo16(u1), v3 = hi16(u1);
        al0 = fmaf(qa.x, v0, al0); al0 = fmaf(qa.y, v1, al0);
        al0 = fmaf(qa.z, v2, al0); al0 = fmaf(qa.w, v3, al0);
        al1 = fmaf(qb.x, v0, al1); al1 = fmaf(qb.y, v1, al1);
        al1 = fmaf(qb.z, v2, al1); al1 = fmaf(qb.w, v3, al1);
      }
      sNUM[half * 64 + lane] = al0;
      sNUM[128 + half * 64 + lane] = al1;
    }

    if (wv == 0) {
      if (isRoot) root_adv(ring, mirr, sCONDW, lane, t + 1, 1, cnt, bits, cprev, rc);
      else        mirr_refresh(myMirr, sCONDW, lane, cnt, bits);
    }
    __syncthreads();
  }

  if (wv == 0) {
    if (isRoot) {
      while (cnt < LL) {
        unsigned long long ds;
        if (!sweep_try(ring, cnt, lane, cprev, ds, SPIN_MAND)) ds = 0;
        cprev = ds > GATE_SUM; rc += cprev ? 1 : 0;
        bits = (bits << 1) | (cprev ? 1u : 0u); ++cnt;
        unsigned long long mv = ((unsigned long long)cnt << 32) | bits;
        for (int i = lane; i < 256; i += 64)
          __hip_atomic_store(mirr + (size_t)i * 8, mv,
                             __ATOMIC_RELAXED, __HIP_MEMORY_SCOPE_AGENT);
        if (lane == 0) *sCONDW = ((unsigned)cnt << 8) | (bits & 0xFFu);
      }
      if (lane == 0) out[BB * 64] = (float)rc / (float)LL;
    } else {
      int guard = SPIN_POLL;
      while (cnt < LL - 1) {
        mirr_refresh(myMirr, sCONDW, lane, cnt, bits);
        if (cnt >= LL - 1) break;
        if (--guard <= 0) break;
        __builtin_amdgcn_s_sleep(8);
      }
      if (lane == 0) *sCONDW = ((unsigned)cnt << 8) | (bits & 0xFFu);
    }
  }

  if (isA) {
    unsigned cv; int guard = SPIN_LDS;
    for (;;) {
      cv = *sCONDW;
      if ((int)(cv >> 8) >= LL - 1) break;
      if (--guard <= 0) break;
      __builtin_amdgcn_s_sleep(1);
    }
    int off = (int)(cv >> 8) - (LL - 1);
    bool c = (off >= 0 && off < 8) ? (((cv >> off) & 1u) != 0u) : false;
    const float* hf = c ? sH1me : sH0me;
    float lof = hb_l;
#pragma unroll 8
    for (int h = 0; h < 64; ++h) lof = fmaf(hf[h], head_w[lane * 64 + h], lof);
    out[(size_t)b * 64 + lane] = lof;
  }
}

// =====================================================================
extern "C" void kernel_launch(void* const* d_in, const int* in_sizes, int n_in,
                              void* d_out, int out_size, void* d_ws, size_t ws_size,
                              hipStream_t stream)
{
  (void)in_sizes; (void)n_in; (void)out_size; (void)ws_size;
  const int*   seq    = (const int*)  d_in[0];
  const float* memory = (const float*)d_in[1];
  const float* embed  = (const float*)d_in[2];
  const float* w_ih   = (const float*)d_in[3];
  const float* w_hh   = (const float*)d_in[4];
  const float* b_ih   = (const float*)d_in[5];
  const float* b_hh   = (const float*)d_in[6];
  const float* wq     = (const float*)d_in[7];
  const float* bq     = (const float*)d_in[8];
  const float* wk     = (const float*)d_in[9];
  const float* bk     = (const float*)d_in[10];
  const float* wv     = (const float*)d_in[11];
  const float* bv     = (const float*)d_in[12];
  const float* head_w = (const float*)d_in[13];
  const float* head_b = (const float*)d_in[14];
  unsigned char* ws   = (unsigned char*)d_ws;
  float* out          = (float*)d_out;

  // zero ring + mirrors + speculation flag every call (graph-safe)
  hipMemsetAsync(d_ws, 0, 32832, stream);

  hipLaunchKernelGGL(reactive_pre, dim3(1), dim3(1024), 0, stream,
                     embed, w_ih, w_hh, b_ih, wq, bq, wk, bk, head_w, ws);

  hipFuncSetAttribute((const void*)reactive_fast,
                      hipFuncAttributeMaxDynamicSharedMemorySize, LDS_BYTES);
  hipLaunchKernelGGL(reactive_fast, dim3(256), dim3(512), LDS_BYTES, stream,
                     seq, memory, wv, bv, b_hh, head_w, head_b, ws, out);

  hipFuncSetAttribute((const void*)reactive_full,
                      hipFuncAttributeMaxDynamicSharedMemorySize, LDS_BYTES);
  hipLaunchKernelGGL(reactive_full, dim3(256), dim3(512), LDS_BYTES, stream,
                     seq, memory, wv, bv, b_hh, head_w, head_b, ws, out);
}